// Round 10
// baseline (190.073 us; speedup 1.0000x reference)
//
#include <hip/hip_runtime.h>
#include <hip/hip_bf16.h>

// CostAttention on MI355X — round 23: cooperative same-chunk attn_main.
// R22 post-mortem: prep occupancy no-op; corrected L2 math (27% util, not
// bound). attn limiter = 2 waves/SIMD (192 unified regs) + 1.56-round grid.
// Fix: all 8 waves share each 64-m chunk. Wave w: S-role (h'=w>>2 m-half,
// rs=w&3 r-strip) and PV-role (ct-pair cp=w>>2, rv=w&3). Each (ct,rs) output
// sub-tile has ONE owner -> oacc 64->8 regs, combine loop deleted. Total regs
// ~95-110 -> (512,2) -> 4 waves/SIMD, 400 blocks all co-resident.
// K chunk (Kh+Kl, 16KB) reg-staged into LDS once per block-iter (stores issued
// during PV, drained by the iter-end barrier). Q frags in regs (loop-invar).
// V frags direct from L2 at S-phase top. l-sum computed PV-side from rounded
// pf (numerically identical to old ones-MFMA). 2 barriers x 100 iters.
// All index mappings verbatim from the verified R14 kernel (s -> rs).
// prep unchanged (R22).
//
// ws layout: shorts [Qh][Ql][Kh][Kl][Vh], each SZ = 1,638,400 shorts (16.4MB).
//   Q/K chunk  ((b*400+mi)*2+c0)*512 + lane*8 : elem [r=16mi+l16][c=32c0+8qq+j]
//   V   chunk  (((b*100+i64)*8)+ct*2+mh)*512 + lane*8 : elem [c=16ct+l16][m=64i64+32mh+8qq+j]

#define NPIX 6400
#define SZ 1638400
#define SHIFT2 11.541560327111707f   // 8 * log2(e)

typedef float f32x4 __attribute__((ext_vector_type(4)));
typedef short bf16x8 __attribute__((ext_vector_type(8)));

#if defined(__has_builtin)
#if __has_builtin(__builtin_amdgcn_exp2f)
#define EXP2(x) __builtin_amdgcn_exp2f(x)
#endif
#endif
#ifndef EXP2
#define EXP2(x) exp2f(x)
#endif

__device__ __forceinline__ void split2(float x, short& h, short& l) {
  unsigned xb = __float_as_uint(x);
  h = (short)(xb >> 16);
  float r = x - __uint_as_float(xb & 0xffff0000u);
  l = (short)(__float_as_uint(r) >> 16);
}

__device__ __forceinline__ short rne_bf16(float x) {
  unsigned u = __float_as_uint(x);
  return (short)((u + 0x7fffu + ((u >> 16) & 1u)) >> 16);
}

__device__ __forceinline__ unsigned pk2(float a, float b) {
  __hip_bfloat162 t = __float22bfloat162_rn(make_float2(a, b));
  unsigned r;
  __builtin_memcpy(&r, &t, 4);
  return r;
}

__device__ __forceinline__ float bf2f(short s) {
  unsigned u = ((unsigned)(unsigned short)s) << 16;
  return __uint_as_float(u);
}

// ---------------- prep (unchanged R22) --------------------------------------
// grid 1000: [0,400) K (b,m-tile) | [400,800) Q-proj (b,r-tile) | [800,1000) V
__global__ __launch_bounds__(256, 4) void prep(
    const float* __restrict__ query, const float* __restrict__ keys,
    const float* __restrict__ values, const float* __restrict__ Wq,
    const float* __restrict__ bq, short* __restrict__ ws)
{
  const int tid = threadIdx.x;
  const int w = tid >> 6;
  const int lane = tid & 63, l16 = lane & 15, qq = lane >> 4;
  short* Qh = ws;          short* Ql = ws + SZ;
  short* Kh = ws + 2 * SZ; short* Kl = ws + 3 * SZ;
  short* Vh = ws + 4 * SZ;
  const int x = blockIdx.x;

  __shared__ float T[64 * 65];

  if (x < 400) {                      // ---- K split (trunc hi/lo, 3-term S)
    const int b = x / 100, t64 = x % 100;
    const int m0 = t64 * 64;
    const float* kb = keys + (size_t)b * 64 * NPIX;
    {
      const int ch = tid >> 2, ml = (tid & 3) * 4;
      const float* src = kb + (size_t)ch * NPIX + m0 + ml;
      #pragma unroll
      for (int u = 0; u < 4; ++u)
        *(float4*)&T[ch * 65 + ml + 16 * u] = *(const float4*)(src + 16 * u);
    }
    __syncthreads();
    const int mi = t64 * 4 + w;
    #pragma unroll
    for (int c0 = 0; c0 < 2; ++c0) {
      float t[8];
      #pragma unroll
      for (int j = 0; j < 8; ++j)
        t[j] = T[(32 * c0 + 8 * qq + j) * 65 + 16 * w + l16];
      bf16x8 h8, l8;
      #pragma unroll
      for (int j = 0; j < 8; ++j) { short h, l; split2(t[j], h, l); h8[j] = h; l8[j] = l; }
      const int off = ((b * 400 + mi) * 2 + c0) * 512 + lane * 8;
      *(bf16x8*)(Kh + off) = h8;
      *(bf16x8*)(Kl + off) = l8;
    }
  } else if (x < 800) {               // ---- Q projection + trunc hi/lo split
    const int y = x - 400;
    const int b = y / 100, t64 = y % 100;
    const int r0 = t64 * 64;
    const float* qb = query + (size_t)b * 64 * NPIX;
    {
      const int ch = tid >> 2, ml = (tid & 3) * 4;
      const float* src = qb + (size_t)ch * NPIX + r0 + ml;
      #pragma unroll
      for (int u = 0; u < 4; ++u)
        *(float4*)&T[ch * 65 + ml + 16 * u] = *(const float4*)(src + 16 * u);
    }
    __syncthreads();

    {
      float xv[64];
      #pragma unroll
      for (int cin = 0; cin < 64; ++cin)
        xv[cin] = T[cin * 65 + lane];
      __syncthreads();   // all xv reads done before T is overwritten

      #pragma unroll 4
      for (int c16 = 0; c16 < 16; ++c16) {
        const int co = __builtin_amdgcn_readfirstlane(16 * w + c16);
        const float* row = Wq + co * 64;
        float a = 0.f;
        #pragma unroll
        for (int cin = 0; cin < 64; ++cin)
          a += row[cin] * xv[cin];
        // scale = (1/8)*log2(e): S in log2 domain -> raw exp2 in main
        T[co * 65 + lane] = (a + bq[co]) * 0.18033688011112042f;
      }
    }
    __syncthreads();

    const int mi = t64 * 4 + w;
    #pragma unroll
    for (int c0 = 0; c0 < 2; ++c0) {
      float t[8];
      #pragma unroll
      for (int j = 0; j < 8; ++j)
        t[j] = T[(32 * c0 + 8 * qq + j) * 65 + 16 * w + l16];
      bf16x8 h8, l8;
      #pragma unroll
      for (int j = 0; j < 8; ++j) { short h, l; split2(t[j], h, l); h8[j] = h; l8[j] = l; }
      const int off = ((b * 400 + mi) * 2 + c0) * 512 + lane * 8;
      *(bf16x8*)(Qh + off) = h8;
      *(bf16x8*)(Ql + off) = l8;
    }
  } else {                            // ---- V: RNE bf16, hi only
    const int gw = (x - 800) * 4 + w;
    const int b = gw / 200, rest = gw % 200;
    const int i = rest / 2, half = rest % 2;
    const float* vb = values + (size_t)b * 64 * NPIX;
    #pragma unroll
    for (int cc = 0; cc < 2; ++cc) {
      const int ct = 2 * half + cc;
      #pragma unroll
      for (int mh = 0; mh < 2; ++mh) {
        const float* vp = vb + (size_t)(16 * ct + l16) * NPIX + 64 * i + 32 * mh + 8 * qq;
        const float4 a  = *(const float4*)vp;
        const float4 b4 = *(const float4*)(vp + 4);
        const float t[8] = {a.x, a.y, a.z, a.w, b4.x, b4.y, b4.z, b4.w};
        bf16x8 h8;
        #pragma unroll
        for (int j = 0; j < 8; ++j) h8[j] = rne_bf16(t[j]);
        const int off = (((b * 100 + i) * 8) + ct * 2 + mh) * 512 + lane * 8;
        *(bf16x8*)(Vh + off) = h8;
      }
    }
  }
}

// ---------------- main: 400 blocks x 512 thr; cooperative 64-m chunks -------
// LDS map (bytes): KST 16384 @0 (Kh 8192 | Kl 8192) ; P 8192 @16384 (2 tiles
// of 4096, tile h = 32-m half) ; LST 512 @24576 -> smem 25088.
// OC [64][65] f32 (16640 B) aliases KST+P after the loop.
__global__ __launch_bounds__(512, 2) void attn_main(
    const short* __restrict__ ws, float* __restrict__ out)
{
  const int tid  = threadIdx.x;
  const int w    = tid >> 6;          // wave 0..7
  const int lane = tid & 63;
  const int l16  = lane & 15, qq = lane >> 4;
  const int hp   = w >> 2;            // S-role: m-half of the 64-m chunk
  const int rs   = w & 3;             // S-role: r-strip
  const int cp   = w >> 2;            // PV-role: ct-pair
  const int rv   = w & 3;             // PV-role: r-strip
  const int x = blockIdx.x;
  const int b      = x & 3;           // batch -> XCDs {b, b+4}
  const int rowjob = x >> 2;          // 0..99
  const int rb     = rowjob * 64;

  const short* Qh = ws;
  const short* Kh = ws + 2 * SZ;
  const short* Vh = ws + 4 * SZ;
  float* ob = out + (size_t)b * 64 * NPIX;

  __shared__ char smem[25088];
  short* KST = (short*)smem;                 // staged K chunk: Kh[4096] Kl[4096] shorts
  short* Ps  = ((short*)smem) + 8192;        // P tiles: hp*2048 shorts each
  float* LST = (float*)(smem + 24576);       // [8 waves][16] (only w<4 used)
  float* OC  = (float*)smem;                 // alias (combine phase)

  // ---- Q frags for this wave's strip rs: hi+lo, loop-invariant, in regs
  bf16x8 qh[2], ql[2];
  {
    const short* qp = Qh + (size_t)((b * 400 + rowjob * 4 + rs) * 2) * 512 + lane * 8;
    #pragma unroll
    for (int c0 = 0; c0 < 2; ++c0) {
      qh[c0] = *(const bf16x8*)(qp + c0 * 512);
      ql[c0] = *(const bf16x8*)(qp + SZ + c0 * 512);
    }
  }

  f32x4 zero4 = {0.f, 0.f, 0.f, 0.f};
  f32x4 oacc[2];
  oacc[0] = zero4; oacc[1] = zero4;
  float lsum = 0.f;

  // ---- stage chunk 0 (each thread: 1 KB segment via w; Kh then Kl)
  {
    const short* gk = Kh + (size_t)(b * 400) * 1024;   // chunk 0 base (mi=0..3)
    bf16x8 s0 = *(const bf16x8*)(gk + w * 512 + lane * 8);
    bf16x8 s1 = *(const bf16x8*)(gk + SZ + w * 512 + lane * 8);
    *(bf16x8*)(KST + w * 512 + lane * 8) = s0;
    *(bf16x8*)(KST + 4096 + w * 512 + lane * 8) = s1;
  }
  __syncthreads();

  for (int i = 0; i < 100; ++i) {
    // ---- issue V loads for this iter's PV (covered by S phase)
    bf16x8 vfh[2][2];
    {
      const short* vp = Vh + (size_t)((b * 100 + i) * 8) * 512 + lane * 8;
      #pragma unroll
      for (int cti = 0; cti < 2; ++cti)
        #pragma unroll
        for (int mh = 0; mh < 2; ++mh)
          vfh[cti][mh] = *(const bf16x8*)(vp + ((2 * cp + cti) * 2 + mh) * 512);
    }

    // ---- S phase: wave computes S[mt=2hp+dt][rs] for dt=0,1 (3-term)
    f32x4 a0 = zero4, a1 = zero4;
    #pragma unroll
    for (int c0 = 0; c0 < 2; ++c0) {
      const bf16x8 kh0 = *(const bf16x8*)(KST + ((2 * hp + 0) * 2 + c0) * 512 + lane * 8);
      const bf16x8 kl0 = *(const bf16x8*)(KST + 4096 + ((2 * hp + 0) * 2 + c0) * 512 + lane * 8);
      const bf16x8 kh1 = *(const bf16x8*)(KST + ((2 * hp + 1) * 2 + c0) * 512 + lane * 8);
      const bf16x8 kl1 = *(const bf16x8*)(KST + 4096 + ((2 * hp + 1) * 2 + c0) * 512 + lane * 8);
      a0 = __builtin_amdgcn_mfma_f32_16x16x32_bf16(kh0, qh[c0], a0, 0, 0, 0);
      a0 = __builtin_amdgcn_mfma_f32_16x16x32_bf16(kh0, ql[c0], a0, 0, 0, 0);
      a0 = __builtin_amdgcn_mfma_f32_16x16x32_bf16(kl0, qh[c0], a0, 0, 0, 0);
      a1 = __builtin_amdgcn_mfma_f32_16x16x32_bf16(kh1, qh[c0], a1, 0, 0, 0);
      a1 = __builtin_amdgcn_mfma_f32_16x16x32_bf16(kh1, ql[c0], a1, 0, 0, 0);
      a1 = __builtin_amdgcn_mfma_f32_16x16x32_bf16(kl1, qh[c0], a1, 0, 0, 0);
    }

    // ---- softmax for this wave's 32-m x 16-r tile -> P tile hp
    {
      short* PW = Ps + hp * 2048;
      float p0 = EXP2(a0[0] - SHIFT2), p1 = EXP2(a0[1] - SHIFT2);
      float p2 = EXP2(a0[2] - SHIFT2), p3 = EXP2(a0[3] - SHIFT2);
      float p4 = EXP2(a1[0] - SHIFT2), p5 = EXP2(a1[1] - SHIFT2);
      float p6 = EXP2(a1[2] - SHIFT2), p7 = EXP2(a1[3] - SHIFT2);
      union { unsigned u[2]; short4 s4; } ua, ub;
      ua.u[0] = pk2(p0, p1); ua.u[1] = pk2(p2, p3);
      ub.u[0] = pk2(p4, p5); ub.u[1] = pk2(p6, p7);
      const int gbase = (rs * 4 + (qq >> 1)) * 16 + l16;
      *(short4*)(PW + (gbase * 8 + 4 * (qq & 1))) = ua.s4;
      *(short4*)(PW + ((gbase + 32) * 8 + 4 * (qq & 1))) = ub.s4;
    }
    __syncthreads();   // bar1: P ready; K-stage reads done

    // ---- issue K stage loads for chunk i+1 (written after PV)
    bf16x8 s0, s1;
    {
      const int inext = (i == 99) ? i : i + 1;
      const short* gk = Kh + (size_t)(b * 400 + 4 * inext) * 1024;
      s0 = *(const bf16x8*)(gk + w * 512 + lane * 8);
      s1 = *(const bf16x8*)(gk + SZ + w * 512 + lane * 8);
    }

    // ---- PV phase: wave computes O^T[ct=2cp+cti][rv] over both m-halves
    {
      const bf16x8 pf0 = *(const bf16x8*)(Ps + ((rv * 4 + qq) * 16 + l16) * 8);
      const bf16x8 pf1 = *(const bf16x8*)(Ps + 2048 + ((rv * 4 + qq) * 16 + l16) * 8);
      #pragma unroll
      for (int cti = 0; cti < 2; ++cti) {
        oacc[cti] = __builtin_amdgcn_mfma_f32_16x16x32_bf16(vfh[cti][0], pf0, oacc[cti], 0, 0, 0);
        oacc[cti] = __builtin_amdgcn_mfma_f32_16x16x32_bf16(vfh[cti][1], pf1, oacc[cti], 0, 0, 0);
      }
      // l-sum from rounded P (cp==0 waves only; matches old ones-MFMA numerics)
      if (cp == 0) {
        float t = 0.f;
        #pragma unroll
        for (int j = 0; j < 8; ++j) t += bf2f(pf0[j]);
        #pragma unroll
        for (int j = 0; j < 8; ++j) t += bf2f(pf1[j]);
        lsum += t;
      }
    }

    // ---- write staged K for next iter (deps: loads s0/s1; drained by bar2)
    *(bf16x8*)(KST + w * 512 + lane * 8) = s0;
    *(bf16x8*)(KST + 4096 + w * 512 + lane * 8) = s1;
    __syncthreads();   // bar2: stage visible; P consumed
  }

  // ---- l reduction: lanes share r = 16*rv + l16 across qq groups
  if (cp == 0) {
    lsum += __shfl_xor(lsum, 16);
    lsum += __shfl_xor(lsum, 32);
    if (qq == 0) LST[rv * 16 + l16] = lsum;
  }
  __syncthreads();   // LST ready; loop LDS free for OC

  // ---- each wave writes its 2 owned sub-tiles (no cross-wave accumulation)
  #pragma unroll
  for (int cti = 0; cti < 2; ++cti)
    #pragma unroll
    for (int r = 0; r < 4; ++r) {
      const int c = 16 * (2 * cp + cti) + 4 * qq + r;
      OC[c * 65 + 16 * rv + l16] = oacc[cti][r];
    }
  __syncthreads();

  // ---- final scale + coalesced store: 512 threads, 8 channels each
  {
    const int r  = tid & 63;
    const int cg = tid >> 6;          // 0..7
    const float inv = 1.0f / LST[(r >> 4) * 16 + (r & 15)];
    #pragma unroll
    for (int u = 0; u < 8; ++u) {
      const int c = cg * 8 + u;
      ob[(size_t)c * NPIX + rb + r] = OC[c * 65 + r] * inv;
    }
  }
}

extern "C" void kernel_launch(void* const* d_in, const int* in_sizes, int n_in,
                              void* d_out, int out_size, void* d_ws, size_t ws_size,
                              hipStream_t stream) {
  const float* query  = (const float*)d_in[0];
  const float* keys   = (const float*)d_in[1];
  const float* values = (const float*)d_in[2];
  const float* Wq     = (const float*)d_in[3];
  const float* bq     = (const float*)d_in[4];
  short* ws = (short*)d_ws;           // 5*SZ*2 = 16.4 MB
  prep<<<dim3(1000), dim3(256), 0, stream>>>(query, keys, values, Wq, bq, ws);
  attn_main<<<dim3(400), dim3(512), 0, stream>>>(ws, (float*)d_out);
}

// Round 11
// 180.041 us; speedup vs baseline: 1.0557x; 1.0557x over previous
//
#include <hip/hip_runtime.h>
#include <hip/hip_bf16.h>

// CostAttention on MI355X — round 24: 32-row jobs, 4-wave blocks, no barriers.
// R23 post-mortem: cooperative lockstep REGRESSED (125us) — 200 barriers
// around 10-MFMA phases ate the occupancy gain. Also: scheduler is work-
// conserving (400x67us/256CU = 104.7 = measured 105) -> no quantization loss
// exists; only per-block speed matters.
// Synthesis: keep R14's barrier-free independent waves, halve per-wave state:
// 800 blocks x 256 thr; block = (b, 32-row job); wave w owns chunks
// [50w,50w+50) alone. oacc [4][2]=32 AGPR + lacc 8; Q-hi AND Q-lo in LDS
// (R19: loop-invariant LDS reads are free; -32 VGPR) -> ~118 unified regs
// -> (256,4) = 4 waves/SIMD, 16 waves/CU (2x TLP). K L2 redundancy 2x (~54%
// of ceiling, safe). All index formulas = verified R14 with s-range 4->2,
// OC stride 65->33. prep unchanged (R22).
//
// ws layout: shorts [Qh][Ql][Kh][Kl][Vh], each SZ = 1,638,400 shorts (16.4MB).
//   Q/K chunk  ((b*400+mi)*2+c0)*512 + lane*8 : elem [r=16mi+l16][c=32c0+8qq+j]
//   V   chunk  (((b*100+i64)*8)+ct*2+mh)*512 + lane*8 : elem [c=16ct+l16][m=64i64+32mh+8qq+j]

#define NPIX 6400
#define SZ 1638400
#define SHIFT2 11.541560327111707f   // 8 * log2(e)

typedef float f32x4 __attribute__((ext_vector_type(4)));
typedef short bf16x8 __attribute__((ext_vector_type(8)));

#if defined(__has_builtin)
#if __has_builtin(__builtin_amdgcn_sched_barrier)
#define SCHED_FENCE() __builtin_amdgcn_sched_barrier(0)
#endif
#if __has_builtin(__builtin_amdgcn_exp2f)
#define EXP2(x) __builtin_amdgcn_exp2f(x)
#endif
#endif
#ifndef SCHED_FENCE
#define SCHED_FENCE()
#endif
#ifndef EXP2
#define EXP2(x) exp2f(x)
#endif

__device__ __forceinline__ void split2(float x, short& h, short& l) {
  unsigned xb = __float_as_uint(x);
  h = (short)(xb >> 16);
  float r = x - __uint_as_float(xb & 0xffff0000u);
  l = (short)(__float_as_uint(r) >> 16);
}

__device__ __forceinline__ short rne_bf16(float x) {
  unsigned u = __float_as_uint(x);
  return (short)((u + 0x7fffu + ((u >> 16) & 1u)) >> 16);
}

__device__ __forceinline__ unsigned pk2(float a, float b) {
  __hip_bfloat162 t = __float22bfloat162_rn(make_float2(a, b));
  unsigned r;
  __builtin_memcpy(&r, &t, 4);
  return r;
}

// ---------------- prep (unchanged R22) --------------------------------------
// grid 1000: [0,400) K (b,m-tile) | [400,800) Q-proj (b,r-tile) | [800,1000) V
__global__ __launch_bounds__(256, 4) void prep(
    const float* __restrict__ query, const float* __restrict__ keys,
    const float* __restrict__ values, const float* __restrict__ Wq,
    const float* __restrict__ bq, short* __restrict__ ws)
{
  const int tid = threadIdx.x;
  const int w = tid >> 6;
  const int lane = tid & 63, l16 = lane & 15, qq = lane >> 4;
  short* Qh = ws;          short* Ql = ws + SZ;
  short* Kh = ws + 2 * SZ; short* Kl = ws + 3 * SZ;
  short* Vh = ws + 4 * SZ;
  const int x = blockIdx.x;

  __shared__ float T[64 * 65];

  if (x < 400) {                      // ---- K split (trunc hi/lo, 3-term S)
    const int b = x / 100, t64 = x % 100;
    const int m0 = t64 * 64;
    const float* kb = keys + (size_t)b * 64 * NPIX;
    {
      const int ch = tid >> 2, ml = (tid & 3) * 4;
      const float* src = kb + (size_t)ch * NPIX + m0 + ml;
      #pragma unroll
      for (int u = 0; u < 4; ++u)
        *(float4*)&T[ch * 65 + ml + 16 * u] = *(const float4*)(src + 16 * u);
    }
    __syncthreads();
    const int mi = t64 * 4 + w;
    #pragma unroll
    for (int c0 = 0; c0 < 2; ++c0) {
      float t[8];
      #pragma unroll
      for (int j = 0; j < 8; ++j)
        t[j] = T[(32 * c0 + 8 * qq + j) * 65 + 16 * w + l16];
      bf16x8 h8, l8;
      #pragma unroll
      for (int j = 0; j < 8; ++j) { short h, l; split2(t[j], h, l); h8[j] = h; l8[j] = l; }
      const int off = ((b * 400 + mi) * 2 + c0) * 512 + lane * 8;
      *(bf16x8*)(Kh + off) = h8;
      *(bf16x8*)(Kl + off) = l8;
    }
  } else if (x < 800) {               // ---- Q projection + trunc hi/lo split
    const int y = x - 400;
    const int b = y / 100, t64 = y % 100;
    const int r0 = t64 * 64;
    const float* qb = query + (size_t)b * 64 * NPIX;
    {
      const int ch = tid >> 2, ml = (tid & 3) * 4;
      const float* src = qb + (size_t)ch * NPIX + r0 + ml;
      #pragma unroll
      for (int u = 0; u < 4; ++u)
        *(float4*)&T[ch * 65 + ml + 16 * u] = *(const float4*)(src + 16 * u);
    }
    __syncthreads();

    {
      float xv[64];
      #pragma unroll
      for (int cin = 0; cin < 64; ++cin)
        xv[cin] = T[cin * 65 + lane];
      __syncthreads();   // all xv reads done before T is overwritten

      #pragma unroll 4
      for (int c16 = 0; c16 < 16; ++c16) {
        const int co = __builtin_amdgcn_readfirstlane(16 * w + c16);
        const float* row = Wq + co * 64;
        float a = 0.f;
        #pragma unroll
        for (int cin = 0; cin < 64; ++cin)
          a += row[cin] * xv[cin];
        // scale = (1/8)*log2(e): S in log2 domain -> raw exp2 in main
        T[co * 65 + lane] = (a + bq[co]) * 0.18033688011112042f;
      }
    }
    __syncthreads();

    const int mi = t64 * 4 + w;
    #pragma unroll
    for (int c0 = 0; c0 < 2; ++c0) {
      float t[8];
      #pragma unroll
      for (int j = 0; j < 8; ++j)
        t[j] = T[(32 * c0 + 8 * qq + j) * 65 + 16 * w + l16];
      bf16x8 h8, l8;
      #pragma unroll
      for (int j = 0; j < 8; ++j) { short h, l; split2(t[j], h, l); h8[j] = h; l8[j] = l; }
      const int off = ((b * 400 + mi) * 2 + c0) * 512 + lane * 8;
      *(bf16x8*)(Qh + off) = h8;
      *(bf16x8*)(Ql + off) = l8;
    }
  } else {                            // ---- V: RNE bf16, hi only
    const int gw = (x - 800) * 4 + w;
    const int b = gw / 200, rest = gw % 200;
    const int i = rest / 2, half = rest % 2;
    const float* vb = values + (size_t)b * 64 * NPIX;
    #pragma unroll
    for (int cc = 0; cc < 2; ++cc) {
      const int ct = 2 * half + cc;
      #pragma unroll
      for (int mh = 0; mh < 2; ++mh) {
        const float* vp = vb + (size_t)(16 * ct + l16) * NPIX + 64 * i + 32 * mh + 8 * qq;
        const float4 a  = *(const float4*)vp;
        const float4 b4 = *(const float4*)(vp + 4);
        const float t[8] = {a.x, a.y, a.z, a.w, b4.x, b4.y, b4.z, b4.w};
        bf16x8 h8;
        #pragma unroll
        for (int j = 0; j < 8; ++j) h8[j] = rne_bf16(t[j]);
        const int off = (((b * 100 + i) * 8) + ct * 2 + mh) * 512 + lane * 8;
        *(bf16x8*)(Vh + off) = h8;
      }
    }
  }
}

// ---------------- main: 800 blocks x 256 thr (4 waves); 32-row jobs ---------
// Wave w owns m-chunks [50w, 50w+50), fully independent (no loop barriers).
// LDS (bytes): P 4x2048=8192 @0 | QH 4096 @8192 | QL 4096 @12288 |
//              LST [4][32] f32 = 512 @16384 -> smem 16896.
// OC [64][33] f32 (8448 B) aliases P+QH after the loop.
__global__ __launch_bounds__(256, 4) void attn_main(
    const short* __restrict__ ws, float* __restrict__ out)
{
  const int tid  = threadIdx.x;
  const int w    = tid >> 6;          // wave 0..3 = m-quarter
  const int lane = tid & 63;
  const int l16  = lane & 15, qq = lane >> 4;
  const int x = blockIdx.x;
  const int b    = x & 3;             // batch -> XCD spread
  const int rj2  = x >> 2;            // 0..199 (32-row job)
  const int rb   = rj2 * 32;

  const short* Qh = ws;
  const short* Kh = ws + 2 * SZ;
  const short* Vh = ws + 4 * SZ;
  float* ob = out + (size_t)b * 64 * NPIX;

  __shared__ char smem[16896];
  short* P   = ((short*)smem) + (w << 10);   // wave-private 1024 shorts (128 rows x 8)
  short* QH  = ((short*)smem) + 4096;        // byte 8192: 4 frags x 64 lanes x 16B
  short* QL  = ((short*)smem) + 6144;        // byte 12288
  float* OC  = (float*)smem;
  float* LST = (float*)(smem + 16384);       // [4 waves][2 strips][16]

  // stage Q hi+lo frags into LDS (4x redundant across waves, benign)
  {
    const short* qp = Qh + (size_t)((b * 400 + rj2 * 2) * 2) * 512 + lane * 8;
    #pragma unroll
    for (int s = 0; s < 2; ++s)
      #pragma unroll
      for (int c0 = 0; c0 < 2; ++c0) {
        *(bf16x8*)(QH + ((s * 2 + c0) * 64 + lane) * 8) =
            *(const bf16x8*)(qp + (s * 2 + c0) * 512);
        *(bf16x8*)(QL + ((s * 2 + c0) * 64 + lane) * 8) =
            *(const bf16x8*)(qp + SZ + (s * 2 + c0) * 512);
      }
  }
  __syncthreads();

  f32x4 zero4 = {0.f, 0.f, 0.f, 0.f};
  f32x4 oacc[4][2];
  f32x4 lacc[2];
  #pragma unroll
  for (int ct = 0; ct < 4; ++ct)
    #pragma unroll
    for (int s = 0; s < 2; ++s) oacc[ct][s] = zero4;
  #pragma unroll
  for (int s = 0; s < 2; ++s) lacc[s] = zero4;

  bf16x8 onesA;
  #pragma unroll
  for (int j = 0; j < 8; ++j) onesA[j] = (short)0x3F80;

  bf16x8 kfh[2][2], kfl[2][2];
  bf16x8 vfh[4];

  auto loadK = [&](int i2) {
    const short* kp = Kh + (size_t)((b * 400 + 2 * i2) * 2) * 512 + lane * 8;
    #pragma unroll
    for (int mt = 0; mt < 2; ++mt)
      #pragma unroll
      for (int c0 = 0; c0 < 2; ++c0) {
        kfh[mt][c0] = *(const bf16x8*)(kp + (mt * 2 + c0) * 512);
        kfl[mt][c0] = *(const bf16x8*)(kp + SZ + (mt * 2 + c0) * 512);
      }
  };
  auto loadV = [&](int i2) {
    const short* vp = Vh + (size_t)((b * 100 + (i2 >> 1)) * 8) * 512 + lane * 8;
    #pragma unroll
    for (int ct = 0; ct < 4; ++ct)
      vfh[ct] = *(const bf16x8*)(vp + (ct * 2 + (i2 & 1)) * 512);
  };

  // wave w owns m-chunks [50w, 50w+50) of 32 m each
  const int i0 = w * 50;
  loadK(i0);
  loadV(i0);

  for (int it = 0; it < 50; ++it) {
    const int i2 = i0 + it;
    const int inext = (it == 49) ? i0 : i2 + 1;

    // ---- both strips' S-MFMAs (4 independent chains), Q from LDS
    f32x4 a0[2], a1[2];
    #pragma unroll
    for (int s = 0; s < 2; ++s) {
      f32x4 t0 = zero4, t1 = zero4;
      #pragma unroll
      for (int c0 = 0; c0 < 2; ++c0) {
        const bf16x8 qh = *(const bf16x8*)(QH + ((s * 2 + c0) * 64 + lane) * 8);
        const bf16x8 ql = *(const bf16x8*)(QL + ((s * 2 + c0) * 64 + lane) * 8);
        t0 = __builtin_amdgcn_mfma_f32_16x16x32_bf16(kfh[0][c0], qh, t0, 0, 0, 0);
        t0 = __builtin_amdgcn_mfma_f32_16x16x32_bf16(kfh[0][c0], ql, t0, 0, 0, 0);
        t0 = __builtin_amdgcn_mfma_f32_16x16x32_bf16(kfl[0][c0], qh, t0, 0, 0, 0);
        t1 = __builtin_amdgcn_mfma_f32_16x16x32_bf16(kfh[1][c0], qh, t1, 0, 0, 0);
        t1 = __builtin_amdgcn_mfma_f32_16x16x32_bf16(kfh[1][c0], ql, t1, 0, 0, 0);
        t1 = __builtin_amdgcn_mfma_f32_16x16x32_bf16(kfl[1][c0], qh, t1, 0, 0, 0);
      }
      a0[s] = t0; a1[s] = t1;
    }

    SCHED_FENCE();
    loadK(inext);
    SCHED_FENCE();

    // ---- softmax: exp2 + packed RNE, P hi-only
    #pragma unroll
    for (int s = 0; s < 2; ++s) {
      float p0 = EXP2(a0[s][0] - SHIFT2), p1 = EXP2(a0[s][1] - SHIFT2);
      float p2 = EXP2(a0[s][2] - SHIFT2), p3 = EXP2(a0[s][3] - SHIFT2);
      float p4 = EXP2(a1[s][0] - SHIFT2), p5 = EXP2(a1[s][1] - SHIFT2);
      float p6 = EXP2(a1[s][2] - SHIFT2), p7 = EXP2(a1[s][3] - SHIFT2);
      union { unsigned u[2]; short4 s4; } ua, ub;
      ua.u[0] = pk2(p0, p1); ua.u[1] = pk2(p2, p3);
      ub.u[0] = pk2(p4, p5); ub.u[1] = pk2(p6, p7);
      const int gbase = (s * 4 + (qq >> 1)) * 16 + l16;
      *(short4*)(P + (gbase * 8 + 4 * (qq & 1))) = ua.s4;
      *(short4*)(P + ((gbase + 32) * 8 + 4 * (qq & 1))) = ub.s4;
    }

    bf16x8 pf[2];
    #pragma unroll
    for (int s = 0; s < 2; ++s)
      pf[s] = *(const bf16x8*)(P + (((s * 4 + qq) * 16 + l16) * 8));

    // ---- O^T += Vh * P^T ; l += 1 * P
    #pragma unroll
    for (int ct = 0; ct < 4; ++ct)
      #pragma unroll
      for (int s = 0; s < 2; ++s)
        oacc[ct][s] = __builtin_amdgcn_mfma_f32_16x16x32_bf16(vfh[ct], pf[s], oacc[ct][s], 0, 0, 0);
    #pragma unroll
    for (int s = 0; s < 2; ++s)
      lacc[s] = __builtin_amdgcn_mfma_f32_16x16x32_bf16(onesA, pf[s], lacc[s], 0, 0, 0);

    SCHED_FENCE();
    loadV(inext);
    SCHED_FENCE();
  }

  // ---------------- in-block combine across the 4 m-quarters ----------------
  if (qq == 0) {
    #pragma unroll
    for (int s = 0; s < 2; ++s) LST[w * 32 + s * 16 + l16] = lacc[s][0];
  }
  __syncthreads();    // loop done; P/QH region free for OC

  #pragma unroll
  for (int wp = 0; wp < 4; ++wp) {
    if (w == wp) {
      #pragma unroll
      for (int ct = 0; ct < 4; ++ct)
        #pragma unroll
        for (int s = 0; s < 2; ++s)
          #pragma unroll
          for (int r = 0; r < 4; ++r) {
            const int c = 16 * ct + 4 * qq + r;
            const int idx = c * 33 + 16 * s + l16;
            if (wp == 0) OC[idx] = oacc[ct][s][r];
            else         OC[idx] += oacc[ct][s][r];
          }
    }
    __syncthreads();
  }

  // final scale + coalesced store: 256 threads, 8 channels each (32 rows)
  {
    const int r  = tid & 31;
    const int cg = tid >> 5;          // 0..7
    float lsum = 0.f;
    #pragma unroll
    for (int w2 = 0; w2 < 4; ++w2)
      lsum += LST[w2 * 32 + (r >> 4) * 16 + (r & 15)];
    const float inv = 1.0f / lsum;
    #pragma unroll
    for (int u = 0; u < 8; ++u) {
      const int c = cg * 8 + u;
      ob[(size_t)c * NPIX + rb + r] = OC[c * 33 + r] * inv;
    }
  }
}

extern "C" void kernel_launch(void* const* d_in, const int* in_sizes, int n_in,
                              void* d_out, int out_size, void* d_ws, size_t ws_size,
                              hipStream_t stream) {
  const float* query  = (const float*)d_in[0];
  const float* keys   = (const float*)d_in[1];
  const float* values = (const float*)d_in[2];
  const float* Wq     = (const float*)d_in[3];
  const float* bq     = (const float*)d_in[4];
  short* ws = (short*)d_ws;           // 5*SZ*2 = 16.4 MB
  prep<<<dim3(1000), dim3(256), 0, stream>>>(query, keys, values, Wq, bq, ws);
  attn_main<<<dim3(800), dim3(256), 0, stream>>>(ws, (float*)d_out);
}